// Round 1
// baseline (74303.131 us; speedup 1.0000x reference)
//
#include <hip/hip_runtime.h>
#include <math.h>

#define T_STEPS 1024
#define BATCH   128
#define INDIM   256
#define HIDIM   512

#define BM 16
#define BN 32
#define BK 32
#define NTH 128

// Accumulate acc[4] += A[BM x K] * W[K x BN] for this block's tile.
// A points at A[row0][0] (stride lda), Wp points at W[0][col0] (stride ldw).
__device__ __forceinline__ void gemm_accum(const float* __restrict__ A, int lda,
                                           const float* __restrict__ Wp, int ldw,
                                           int K, float acc[4],
                                           float (&As)[BM][BK + 1],
                                           float (&Bs)[BK][BN + 1],
                                           int tid)
{
    const int tc = tid & 31;   // output col within tile
    const int tr = tid >> 5;   // output row group (0..3)
    for (int k0 = 0; k0 < K; k0 += BK) {
        __syncthreads();   // protect previous iteration's reads
        // Load A tile: BM*BK = 512 floats, 4 per thread, coalesced in k
        #pragma unroll
        for (int p = 0; p < (BM * BK) / NTH; ++p) {
            int l = tid + p * NTH;
            int i = l >> 5;
            int j = l & 31;
            As[i][j] = A[i * lda + k0 + j];
        }
        // Load B tile: BK*BN = 1024 floats, 8 per thread, coalesced in j
        #pragma unroll
        for (int p = 0; p < (BK * BN) / NTH; ++p) {
            int l = tid + p * NTH;
            int k = l >> 5;
            int j = l & 31;
            Bs[k][j] = Wp[(k0 + k) * ldw + j];
        }
        __syncthreads();
        #pragma unroll
        for (int kk = 0; kk < BK; ++kk) {
            float bv = Bs[kk][tc];
            #pragma unroll
            for (int m = 0; m < 4; ++m) {
                acc[m] += As[tr + m * 4][kk] * bv;
            }
        }
    }
}

__device__ __forceinline__ float sigmoidf_(float x) {
    return 1.0f / (1.0f + expf(-x));
}

// c = relu(state @ W_ch + b_c)
__global__ void ctx_kernel(const float* __restrict__ state,
                           const float* __restrict__ W_ch,
                           const float* __restrict__ b_c,
                           float* __restrict__ c_out)
{
    __shared__ float As[BM][BK + 1];
    __shared__ float Bs[BK][BN + 1];
    const int tid  = threadIdx.x;
    const int col0 = blockIdx.x * BN;
    const int row0 = blockIdx.y * BM;
    float acc[4] = {0.f, 0.f, 0.f, 0.f};
    gemm_accum(state + row0 * HIDIM, HIDIM, W_ch + col0, HIDIM, HIDIM, acc, As, Bs, tid);
    const int tc = tid & 31, tr = tid >> 5;
    const float bj = b_c[col0 + tc];
    #pragma unroll
    for (int m = 0; m < 4; ++m) {
        const int row = row0 + tr + m * 4;
        float v = acc[m] + bj;
        c_out[row * HIDIM + col0 + tc] = v > 0.f ? v : 0.f;
    }
}

// gate==0: z = sigmoid(h@W_zh + x@W_zx + b_z + c)         -> z_out
// gate==1: r = sigmoid(h@W_rh + x@W_rx + b_r + c); rh=r*h -> rh_out
__global__ void zr_kernel(const float* __restrict__ h,
                          const float* __restrict__ x_t,
                          const float* __restrict__ W_zh, const float* __restrict__ W_zx,
                          const float* __restrict__ b_z,
                          const float* __restrict__ W_rh, const float* __restrict__ W_rx,
                          const float* __restrict__ b_r,
                          const float* __restrict__ c,
                          float* __restrict__ z_out, float* __restrict__ rh_out)
{
    __shared__ float As[BM][BK + 1];
    __shared__ float Bs[BK][BN + 1];
    const int tid  = threadIdx.x;
    const int col0 = blockIdx.x * BN;
    const int row0 = blockIdx.y * BM;
    const int gate = blockIdx.z;
    const float* Wh = gate ? W_rh : W_zh;
    const float* Wx = gate ? W_rx : W_zx;
    const float* bb = gate ? b_r  : b_z;
    float acc[4] = {0.f, 0.f, 0.f, 0.f};
    gemm_accum(h   + row0 * HIDIM, HIDIM, Wh + col0, HIDIM, HIDIM, acc, As, Bs, tid);
    gemm_accum(x_t + row0 * INDIM, INDIM, Wx + col0, HIDIM, INDIM, acc, As, Bs, tid);
    const int tc = tid & 31, tr = tid >> 5;
    const float bj = bb[col0 + tc];
    #pragma unroll
    for (int m = 0; m < 4; ++m) {
        const int row = row0 + tr + m * 4;
        const int idx = row * HIDIM + col0 + tc;
        float pre = acc[m] + bj + c[idx];
        float s = sigmoidf_(pre);
        if (gate == 0) z_out[idx] = s;
        else           rh_out[idx] = s * h[idx];
    }
}

// hc = tanh(rh@W_hh + x@W_hx + b_h + c); h_nxt = (1-z)*h + z*hc
__global__ void hu_kernel(const float* __restrict__ rh,
                          const float* __restrict__ x_t,
                          const float* __restrict__ W_hh, const float* __restrict__ W_hx,
                          const float* __restrict__ b_h,
                          const float* __restrict__ c,
                          const float* __restrict__ z,
                          const float* __restrict__ h_cur,
                          float* __restrict__ h_nxt)
{
    __shared__ float As[BM][BK + 1];
    __shared__ float Bs[BK][BN + 1];
    const int tid  = threadIdx.x;
    const int col0 = blockIdx.x * BN;
    const int row0 = blockIdx.y * BM;
    float acc[4] = {0.f, 0.f, 0.f, 0.f};
    gemm_accum(rh  + row0 * HIDIM, HIDIM, W_hh + col0, HIDIM, HIDIM, acc, As, Bs, tid);
    gemm_accum(x_t + row0 * INDIM, INDIM, W_hx + col0, HIDIM, INDIM, acc, As, Bs, tid);
    const int tc = tid & 31, tr = tid >> 5;
    const float bj = b_h[col0 + tc];
    #pragma unroll
    for (int m = 0; m < 4; ++m) {
        const int row = row0 + tr + m * 4;
        const int idx = row * HIDIM + col0 + tc;
        float pre = acc[m] + bj + c[idx];
        float hc = tanhf(pre);
        float zv = z[idx];
        float hv = h_cur[idx];
        h_nxt[idx] = (1.f - zv) * hv + zv * hc;
    }
}

extern "C" void kernel_launch(void* const* d_in, const int* in_sizes, int n_in,
                              void* d_out, int out_size, void* d_ws, size_t ws_size,
                              hipStream_t stream)
{
    const float* input = (const float*)d_in[0];   // [T, B, INDIM]
    const float* state = (const float*)d_in[1];   // [B, HIDIM]
    const float* W_zh  = (const float*)d_in[2];
    const float* W_zx  = (const float*)d_in[3];
    const float* b_z   = (const float*)d_in[4];
    const float* W_rh  = (const float*)d_in[5];
    const float* W_rx  = (const float*)d_in[6];
    const float* b_r   = (const float*)d_in[7];
    const float* W_hh  = (const float*)d_in[8];
    const float* W_hx  = (const float*)d_in[9];
    const float* b_h   = (const float*)d_in[10];
    const float* W_ch  = (const float*)d_in[11];
    const float* b_c   = (const float*)d_in[12];

    float* out = (float*)d_out;                   // [B, HIDIM] = 65536 floats
    float* ws  = (float*)d_ws;

    const int BH = BATCH * HIDIM;                 // 65536
    float* c_buf = ws;
    float* z_buf = ws + BH;
    float* rh_buf= ws + 2 * BH;
    float* hA    = ws + 3 * BH;
    float* hB    = ws + 4 * BH;

    dim3 blk(NTH);
    dim3 grid_g(HIDIM / BN, BATCH / BM);          // (16, 8)
    dim3 grid_zr(HIDIM / BN, BATCH / BM, 2);      // (16, 8, 2)

    ctx_kernel<<<grid_g, blk, 0, stream>>>(state, W_ch, b_c, c_buf);

    const float* h_cur = state;
    for (int t = 0; t < T_STEPS; ++t) {
        const float* x_t = input + (size_t)t * BATCH * INDIM;
        zr_kernel<<<grid_zr, blk, 0, stream>>>(h_cur, x_t,
                                               W_zh, W_zx, b_z,
                                               W_rh, W_rx, b_r,
                                               c_buf, z_buf, rh_buf);
        float* h_nxt = (t == T_STEPS - 1) ? out : ((t & 1) ? hB : hA);
        hu_kernel<<<grid_g, blk, 0, stream>>>(rh_buf, x_t,
                                              W_hh, W_hx, b_h,
                                              c_buf, z_buf, h_cur, h_nxt);
        h_cur = h_nxt;
    }
}